// Round 8
// baseline (477.665 us; speedup 1.0000x reference)
//
#include <hip/hip_runtime.h>

#define NN 8192
#define CC 512
#define DKK 64

typedef float f32x4 __attribute__((ext_vector_type(4)));
typedef float f32x16 __attribute__((ext_vector_type(16)));
typedef _Float16 f16x8 __attribute__((ext_vector_type(8)));
typedef _Float16 f16x4 __attribute__((ext_vector_type(4)));

__device__ __forceinline__ f32x4 mfma16(f16x8 a, f16x8 b, f32x4 c) {
    return __builtin_amdgcn_mfma_f32_16x16x32_f16(a, b, c, 0, 0, 0);
}
__device__ __forceinline__ f32x16 mfma32(f16x8 a, f16x8 b, f32x16 c) {
    return __builtin_amdgcn_mfma_f32_32x32x16_f16(a, b, c, 0, 0, 0);
}
__device__ __forceinline__ f16x8 scl8(f16x8 v, float f) {
    _Float16 h = (_Float16)f;
    f16x8 r;
#pragma unroll
    for (int i = 0; i < 8; i++) r[i] = v[i] * h;
    return r;
}

// ---- all weight transposes in one launch. grid 1280 x 256.
// Wqt: 64*512 = 32768; Wkt: 32768; Wvf: 512*512 = 262144. Total 327680.
__global__ void wtrans_all_kernel(const float* __restrict__ Wq, const float* __restrict__ Wk,
                                  const float* __restrict__ Wv,
                                  _Float16* __restrict__ Wqt, _Float16* __restrict__ Wkt,
                                  _Float16* __restrict__ Wvf) {
    int idx = blockIdx.x * 256 + threadIdx.x;
    if (idx < 32768) {
        int n = idx >> 9, k = idx & 511;
        Wqt[idx] = (_Float16)Wq[k * 64 + n];
    } else if (idx < 65536) {
        int j = idx - 32768;
        int n = j >> 9, k = j & 511;
        Wkt[j] = (_Float16)Wk[k * 64 + n];
    } else {
        int j = idx - 65536;
        int k16 = j & 15, c = (j >> 4) & 511, ks = j >> 13;
        Wvf[j] = (_Float16)Wv[(size_t)(16 * ks + k16) * 512 + c];
    }
}

// ---- fused Q+K projection: Q[N][64] row-major f16; K -> frag-major
// Kf[tile=n>>6][ks=dk>>4][kv6=n&63][k16=dk&15]
__global__ __launch_bounds__(256) void proj_qk2_kernel(
    const float* __restrict__ im1, const float* __restrict__ im2,
    const _Float16* __restrict__ Wqt, const _Float16* __restrict__ Wkt,
    _Float16* __restrict__ Q1, _Float16* __restrict__ Kf1,
    _Float16* __restrict__ Q2, _Float16* __restrict__ Kf2)
{
    const float* X = blockIdx.y ? im2 : im1;
    _Float16* Q = blockIdx.y ? Q2 : Q1;
    _Float16* Kf = blockIdx.y ? Kf2 : Kf1;

    __shared__ __align__(16) _Float16 Wlds[128 * 512];  // 128 KB

    const int tid = threadIdx.x;
    const int lane = tid & 63, wave = tid >> 6;
    const int n16 = lane & 15, quad = lane >> 4;

#pragma unroll
    for (int i = 0; i < 32; i++) {
        const int idx = tid + 256 * i;
        const int row = idx >> 6, ch = idx & 63;
        const _Float16* src = (row < 64) ? (Wqt + (size_t)row * 512 + ch * 8)
                                         : (Wkt + (size_t)(row - 64) * 512 + ch * 8);
        *(f16x8*)&Wlds[row * 512 + ((ch ^ (row & 7)) * 8)] = *(const f16x8*)src;
    }
    __syncthreads();

    const int arow = blockIdx.x * 64 + wave * 16 + n16;
    f32x4 acc[8];
#pragma unroll
    for (int i = 0; i < 8; i++) acc[i] = (f32x4){0.f, 0.f, 0.f, 0.f};

    const float* xbase = X + (size_t)arow * 512 + quad * 8;
    for (int kk = 0; kk < 16; kk++) {
        f32x4 xa = *(const f32x4*)(xbase + kk * 32);
        f32x4 xb = *(const f32x4*)(xbase + kk * 32 + 4);
        f16x8 afrag;
#pragma unroll
        for (int j = 0; j < 4; j++) { afrag[j] = (_Float16)xa[j]; afrag[4 + j] = (_Float16)xb[j]; }
#pragma unroll
        for (int t = 0; t < 8; t++) {
            const int row = t * 16 + n16;
            f16x8 bfr = *(const f16x8*)&Wlds[row * 512 + (((4 * kk + quad) ^ (row & 7)) * 8)];
            acc[t] = mfma16(afrag, bfr, acc[t]);
        }
    }
    const int rbase = blockIdx.x * 64 + wave * 16 + quad * 4;
#pragma unroll
    for (int t = 0; t < 4; t++)
#pragma unroll
        for (int r = 0; r < 4; r++) {
            Q[(size_t)(rbase + r) * 64 + t * 16 + n16] = (_Float16)acc[t][r];
            Kf[((size_t)(blockIdx.x * 4 + t) * 64 + (wave * 16 + quad * 4 + r)) * 16 + n16] =
                (_Float16)acc[4 + t][r];
        }
}

// ---- V projection -> frag-major Vf[tile][ks=n6>>4][c=512][n16]
__global__ __launch_bounds__(256) void proj_vt_kernel(
    const float* __restrict__ im1, const float* __restrict__ im2,
    const _Float16* __restrict__ Wvf,
    _Float16* __restrict__ Vf1, _Float16* __restrict__ Vf2)
{
    const float* X = blockIdx.y ? im2 : im1;
    _Float16* Vf = blockIdx.y ? Vf2 : Vf1;
    const int n0 = blockIdx.x * 32;
    const int tid = threadIdx.x;
    const int lane = tid & 63, wave = tid >> 6;
    const int l31 = lane & 31, lhi = lane >> 5;

    __shared__ __align__(16) _Float16 Xlds[32 * 512];

#pragma unroll
    for (int i = 0; i < 8; i++) {
        const int n = tid >> 3;
        const int chunk = (tid & 7) + 8 * i;
        const float* xp = X + (size_t)(n0 + n) * CC + chunk * 8;
        f32x4 x0 = *(const f32x4*)xp;
        f32x4 x1 = *(const f32x4*)(xp + 4);
        f16x8 d;
#pragma unroll
        for (int j = 0; j < 4; j++) { d[j] = (_Float16)x0[j]; d[4 + j] = (_Float16)x1[j]; }
        *(f16x8*)&Xlds[n * 512 + ((chunk ^ (n & 7)) * 8)] = d;
    }
    __syncthreads();

    f32x16 acc[4];
#pragma unroll
    for (int t = 0; t < 4; t++)
#pragma unroll
        for (int r = 0; r < 16; r++) acc[t][r] = 0.f;

    for (int ks = 0; ks < 32; ks++) {
        f16x8 xb = *(const f16x8*)&Xlds[l31 * 512 + (((2 * ks + lhi) ^ (l31 & 7)) * 8)];
#pragma unroll
        for (int ct = 0; ct < 4; ct++) {
            const _Float16* wp = Wvf + ((size_t)ks * 512 + 128 * wave + 32 * ct + l31) * 16 + 8 * lhi;
            acc[ct] = mfma32(*(const f16x8*)wp, xb, acc[ct]);
        }
    }
    const int tile = n0 >> 6;
    const int ksbase = (n0 & 32) >> 4;  // 0 or 2
#pragma unroll
    for (int ct = 0; ct < 4; ct++)
#pragma unroll
        for (int r = 0; r < 16; r++) {
            const int c = 128 * wave + 32 * ct + (r & 3) + 8 * (r >> 2) + 4 * lhi;
            const int ks = ksbase + (l31 >> 4);
            Vf[((size_t)(tile * 4 + ks) * 512 + c) * 16 + (l31 & 15)] = (_Float16)acc[ct][r];
        }
}

// ---- flash v6: c-split for 2 independent blocks/CU.
// grid (128 qtile, 2 img, 2 chalf), 512 thr = 8 waves: g = wave>>2 (kv parity),
// wg = wave&3; QK: b = wg&1 (q-half), a = wg>>1 (kv-half) -- full softmax per block.
// PV: c-64th 256*chalf + 64*wg, ct<2. QK pipelined 1 slot ahead; chunk-major P.
__global__ __launch_bounds__(512, 4) void flash6_kernel(
    const _Float16* __restrict__ Q1, const _Float16* __restrict__ Kf1,
    const _Float16* __restrict__ Q2, const _Float16* __restrict__ Kf2,
    const _Float16* __restrict__ Vf1, const _Float16* __restrict__ Vf2,
    const float* __restrict__ im1, const float* __restrict__ im2,
    float* __restrict__ out)
{
    const int img = blockIdx.y;
    const int ch = blockIdx.z;
    const _Float16* Q = img ? Q1 : Q2;
    const _Float16* Kf = img ? Kf2 : Kf1;
    const _Float16* Vf = img ? Vf2 : Vf1;
    const float* res = img ? im2 : im1;
    float* o = out + (size_t)img * NN * CC;

    // loop: P[2 bufs][2 g][8 chunk][64 q][8] f16 (32 KB); epilogue alias: Olds f32[64][132]
    __shared__ __align__(16) char smem[64 * 132 * 4];  // 33792 B >= 32768
    __shared__ float mPart[2][2][2][64];  // [buf][g][a][q]
    __shared__ float mF[2][2][64], lF[2][2][64];

    const int tid = threadIdx.x;
    const int lane = tid & 63, wave = tid >> 6;
    const int l31 = lane & 31, lhi = lane >> 5;
    const int g = wave >> 2, wg = wave & 3;
    const int b = wg & 1, a = wg >> 1;
    const int qbase = blockIdx.x * 64;
    const int cbase = 256 * ch + 64 * wg;  // this wave's PV c-base

    _Float16* Pbase = (_Float16*)smem;

    f16x8 qf[4];
    {
        const _Float16* qp = Q + (size_t)(qbase + 32 * b + l31) * DKK + 8 * lhi;
#pragma unroll
        for (int k = 0; k < 4; k++) qf[k] = *(const f16x8*)(qp + 16 * k);
    }

    f32x16 acc[4];  // [ct*2 + qt], ct<2
#pragma unroll
    for (int t = 0; t < 4; t++)
#pragma unroll
        for (int r = 0; r < 16; r++) acc[t][r] = 0.f;
    float ma_run = -3e38f, l_run = 0.f;  // own (g,a) stream
    float mg_run[2] = {-3e38f, -3e38f};  // per qt, acc reference max

    // QK for slot s: compute S^T quarter, softmax vs own stream, write P+mPart.
    auto do_qk = [&](int s) {
        const int t = 2 * s + g;
        const int pbuf = s & 1;
        _Float16* Pg = Pbase + (pbuf * 2 + g) * 4096;
        f32x16 sA;
#pragma unroll
        for (int r = 0; r < 16; r++) sA[r] = 0.f;
#pragma unroll
        for (int k = 0; k < 4; k++) {
            f16x8 kf = *(const f16x8*)(Kf + ((size_t)(t * 4 + k) * 64 + 32 * a + l31) * 16 + 8 * lhi);
            sA = mfma32(kf, qf[k], sA);
        }
        float mx = -3e38f;
#pragma unroll
        for (int r = 0; r < 16; r++) mx = fmaxf(mx, sA[r]);
        mx = fmaxf(mx, __shfl_xor(mx, 32));
        const float manew = fmaxf(ma_run, mx);
        if (lane < 32) mPart[pbuf][g][a][32 * b + lane] = manew;
        float ls = 0.f;
#pragma unroll
        for (int r = 0; r < 16; r++) {
            float p = __expf(sA[r] - manew);
            ls += p;
            sA[r] = p;
        }
        ls += __shfl_xor(ls, 32);
        l_run = l_run * __expf(ma_run - manew) + ls;
        ma_run = manew;
        const int q = 32 * b + l31;
#pragma unroll
        for (int gg = 0; gg < 4; gg++) {
            f16x4 p4;
#pragma unroll
            for (int u = 0; u < 4; u++) p4[u] = (_Float16)sA[gg * 4 + u];
            // chunk-major: P[chunk=4a+gg][q][8], lane offset 4*lhi (contiguous, 0-conflict)
            *(f16x4*)&Pg[((4 * a + gg) * 64 + q) * 8 + 4 * lhi] = p4;
        }
    };

    do_qk(0);
    __syncthreads();

    for (int s = 0; s < 64; s++) {
        const int t = 2 * s + g;
        const int pbuf = s & 1;
        _Float16* Pg = Pbase + (pbuf * 2 + g) * 4096;

        // early V-frag issue for PV(s), k = 0,1 (covers L2 latency under QK(s+1))
        f16x8 va01[4];
#pragma unroll
        for (int k = 0; k < 2; k++)
#pragma unroll
            for (int ct = 0; ct < 2; ct++)
                va01[k * 2 + ct] = *(const f16x8*)(Vf +
                    ((size_t)(t * 4 + k) * 512 + cbase + 32 * ct + l31) * 16 + 8 * lhi);

        // pipelined QK for next slot (writes other P buffer)
        if (s < 63) do_qk(s + 1);

        // ---- PV(s): merge a-streams lazily; dense frag-major V loads
        float al[2], f0[2], f1[2];
#pragma unroll
        for (int qt = 0; qt < 2; qt++) {
            const int q = 32 * qt + l31;
            const float m0 = mPart[pbuf][g][0][q];
            const float m1 = mPart[pbuf][g][1][q];
            const float mgn = fmaxf(mg_run[qt], fmaxf(m0, m1));
            al[qt] = __expf(mg_run[qt] - mgn);
            f0[qt] = __expf(m0 - mgn);
            f1[qt] = __expf(m1 - mgn);
            mg_run[qt] = mgn;
        }
        if (!__all((al[0] == 1.f) & (al[1] == 1.f))) {
#pragma unroll
            for (int ct = 0; ct < 2; ct++)
#pragma unroll
                for (int r = 0; r < 16; r++) {
                    acc[ct * 2 + 0][r] *= al[0];
                    acc[ct * 2 + 1][r] *= al[1];
                }
        }
        const bool noscale =
            __all((f0[0] == 1.f) & (f1[0] == 1.f) & (f0[1] == 1.f) & (f1[1] == 1.f));
#pragma unroll
        for (int k = 0; k < 4; k++) {
            // chunk-major P reads: lanes contiguous, 0-conflict
            f16x8 pb0 = *(const f16x8*)&Pg[((2 * k + lhi) * 64 + l31) * 8];
            f16x8 pb1 = *(const f16x8*)&Pg[((2 * k + lhi) * 64 + 32 + l31) * 8];
            if (!noscale) {
                pb0 = scl8(pb0, k < 2 ? f0[0] : f1[0]);
                pb1 = scl8(pb1, k < 2 ? f0[1] : f1[1]);
            }
#pragma unroll
            for (int ct = 0; ct < 2; ct++) {
                f16x8 va;
                if (k < 2) va = va01[k * 2 + ct];
                else va = *(const f16x8*)(Vf +
                    ((size_t)(t * 4 + k) * 512 + cbase + 32 * ct + l31) * 16 + 8 * lhi);
                acc[ct * 2 + 0] = mfma32(va, pb0, acc[ct * 2 + 0]);
                acc[ct * 2 + 1] = mfma32(va, pb1, acc[ct * 2 + 1]);
            }
        }
        __syncthreads();  // P(s+1)/mPart written by all; P(s) reads done
    }

    // ---- epilogue: merge streams, add residual, store (two c-quarter rounds)
    if (lane < 32) {
        mF[g][a][32 * b + lane] = ma_run;
        lF[g][a][32 * b + lane] = l_run;
    }
    __syncthreads();

    float fac[2];
#pragma unroll
    for (int qt = 0; qt < 2; qt++) {
        const int q = 32 * qt + l31;
        const float m00 = mF[0][0][q], m01 = mF[0][1][q];
        const float m10 = mF[1][0][q], m11 = mF[1][1][q];
        const float M = fmaxf(fmaxf(m00, m01), fmaxf(m10, m11));
        const float den = lF[0][0][q] * __expf(m00 - M) + lF[0][1][q] * __expf(m01 - M) +
                          lF[1][0][q] * __expf(m10 - M) + lF[1][1][q] * __expf(m11 - M);
        fac[qt] = __expf(mg_run[qt] - M) / den;
    }

    float* Olds = (float*)smem;  // [64][132], aliases P (loop is done)
#pragma unroll
    for (int rr = 0; rr < 2; rr++) {
        const bool mine = ((wg >> 1) == rr);
        const int cloc = 64 * (wg & 1);  // c offset within this 128-col round
        __syncthreads();
        if (mine && g == 0) {
#pragma unroll
            for (int ct = 0; ct < 2; ct++)
#pragma unroll
                for (int qt = 0; qt < 2; qt++)
#pragma unroll
                    for (int r = 0; r < 16; r++) {
                        const int c = cloc + 32 * ct + (r & 3) + 8 * (r >> 2) + 4 * lhi;
                        Olds[(32 * qt + l31) * 132 + c] = acc[ct * 2 + qt][r] * fac[qt];
                    }
        }
        __syncthreads();
        if (mine && g == 1) {
#pragma unroll
            for (int ct = 0; ct < 2; ct++)
#pragma unroll
                for (int qt = 0; qt < 2; qt++)
#pragma unroll
                    for (int r = 0; r < 16; r++) {
                        const int c = cloc + 32 * ct + (r & 3) + 8 * (r >> 2) + 4 * lhi;
                        Olds[(32 * qt + l31) * 132 + c] += acc[ct * 2 + qt][r] * fac[qt];
                    }
        }
        __syncthreads();
        {
            const int q = tid >> 3;
            const size_t grow = (size_t)(qbase + q);
            const int cg = 256 * ch + 128 * rr;
#pragma unroll
            for (int i = 0; i < 4; i++) {
                const int cw = ((tid & 7) + 8 * i) * 4;
                f32x4 v = *(const f32x4*)&Olds[q * 132 + cw];
                f32x4 rrv = *(const f32x4*)(res + grow * CC + cg + cw);
                v += rrv;
                *(f32x4*)(o + grow * CC + cg + cw) = v;
            }
        }
    }
}

extern "C" void kernel_launch(void* const* d_in, const int* in_sizes, int n_in,
                              void* d_out, int out_size, void* d_ws, size_t ws_size,
                              hipStream_t stream) {
    const float* im1 = (const float*)d_in[0];
    const float* im2 = (const float*)d_in[1];
    const float* Wq  = (const float*)d_in[2];
    const float* Wk  = (const float*)d_in[3];
    const float* Wv  = (const float*)d_in[4];
    float* out = (float*)d_out;

    _Float16* w = (_Float16*)d_ws;
    _Float16* Wqt = w;                      // 64*512
    _Float16* Wkt = Wqt + 64 * 512;
    _Float16* Wvf = Wkt + 64 * 512;         // 512*512 frag-major
    _Float16* Q1  = Wvf + 512 * 512;        // 8192*64 each
    _Float16* Kf1 = Q1 + NN * DKK;
    _Float16* Q2  = Kf1 + NN * DKK;
    _Float16* Kf2 = Q2 + NN * DKK;
    _Float16* Vf1 = Kf2 + NN * DKK;         // frag-major [128][4][512][16] each
    _Float16* Vf2 = Vf1 + (size_t)CC * NN;

    wtrans_all_kernel<<<1280, 256, 0, stream>>>(Wq, Wk, Wv, Wqt, Wkt, Wvf);
    proj_qk2_kernel<<<dim3(128, 2), 256, 0, stream>>>(im1, im2, Wqt, Wkt, Q1, Kf1, Q2, Kf2);
    proj_vt_kernel<<<dim3(256, 2), 256, 0, stream>>>(im1, im2, Wvf, Vf1, Vf2);
    flash6_kernel<<<dim3(128, 2, 2), 512, 0, stream>>>(Q1, Kf1, Q2, Kf2, Vf1, Vf2, im1, im2, out);
}